// Round 1
// baseline (13981.686 us; speedup 1.0000x reference)
//
#include <hip/hip_runtime.h>

#define S_N 50000
#define E_N 20000
#define K_N 128
#define B_N 16384
#define NE_N 1000000

__device__ __forceinline__ float sigmoidf_(float v) {
    return 1.0f / (1.0f + __expf(-v));
}

// dst[row][k] = src[row][k] * (dA[row] + dB[row]); serves as init (diagonal term)
// for the subsequent atomic scatter-add. One thread per float4; K/4 = 32 float4/row.
__global__ void scale_nodes(const float4* __restrict__ src,
                            const float* __restrict__ dA,
                            const float* __restrict__ dB,
                            float4* __restrict__ dst, int nrow) {
    int i = blockIdx.x * blockDim.x + threadIdx.x;
    if (i >= nrow * (K_N / 4)) return;
    int row = i >> 5;  // / (K/4)
    float d = dA[row] + dB[row];
    float4 v = src[i];
    v.x *= d; v.y *= d; v.z *= d; v.w *= d;
    dst[i] = v;
}

// One edge handled by 32 lanes (each lane owns one float4 of the K=128 row).
// Edge id e in [0, 2*NE): first NE from graph1, rest from graph0.
//   stat_new[r]  += vui[e] * kdiff_old[c]
//   kdiff_new[c] += viu[e] * stat_old[r]
__global__ __launch_bounds__(256) void edge_pass(
    const float* __restrict__ stat_old, const float* __restrict__ kdiff_old,
    float* __restrict__ stat_new, float* __restrict__ kdiff_new,
    const int* __restrict__ rows1, const int* __restrict__ cols1,
    const float* __restrict__ vui1, const float* __restrict__ viu1,
    const int* __restrict__ rows0, const int* __restrict__ cols0,
    const float* __restrict__ vui0, const float* __restrict__ viu0) {
    long long g = (long long)blockIdx.x * blockDim.x + threadIdx.x;
    int e = (int)(g >> 5);
    int lane = (int)(g & 31);
    if (e >= 2 * NE_N) return;

    const int* rows; const int* cols; const float* vui; const float* viu;
    if (e < NE_N) {
        rows = rows1; cols = cols1; vui = vui1; viu = viu1;
    } else {
        e -= NE_N;
        rows = rows0; cols = cols0; vui = vui0; viu = viu0;
    }
    int r = rows[e];
    int c = cols[e];
    float a = vui[e];
    float b = viu[e];

    float4 kv = ((const float4*)(kdiff_old + (size_t)c * K_N))[lane];
    float4 sv = ((const float4*)(stat_old + (size_t)r * K_N))[lane];

    float* sd = stat_new + (size_t)r * K_N + lane * 4;
    float* kd = kdiff_new + (size_t)c * K_N + lane * 4;
    unsafeAtomicAdd(sd + 0, a * kv.x);
    unsafeAtomicAdd(sd + 1, a * kv.y);
    unsafeAtomicAdd(sd + 2, a * kv.z);
    unsafeAtomicAdd(sd + 3, a * kv.w);
    unsafeAtomicAdd(kd + 0, b * sv.x);
    unsafeAtomicAdd(kd + 1, b * sv.y);
    unsafeAtomicAdd(kd + 2, b * sv.z);
    unsafeAtomicAdd(kd + 3, b * sv.w);
}

// One block (256 threads) per batch row: gather + sigmoid feature, then
// 128->256->128->1 PosLinear (|W|) MLP with tanh/tanh/sigmoid.
__global__ __launch_bounds__(256) void predict(
    const int* __restrict__ stu_id, const int* __restrict__ ex_id,
    const float* __restrict__ ikp,
    const float* __restrict__ stat, const float* __restrict__ kdiff,
    const float* __restrict__ s_bias, const float* __restrict__ e_disc,
    const float* __restrict__ W1, const float* __restrict__ b1,
    const float* __restrict__ W2, const float* __restrict__ b2,
    const float* __restrict__ W3, const float* __restrict__ b3,
    float* __restrict__ out) {
    __shared__ __align__(16) float x[128];
    __shared__ __align__(16) float h1[256];
    __shared__ __align__(16) float h2[128];

    int row = blockIdx.x;
    int t = threadIdx.x;
    int s = stu_id[row];
    int e = ex_id[row];
    float ed = sigmoidf_(e_disc[e]);

    if (t < 128) {
        float sb = stat[(size_t)s * K_N + t] + s_bias[s];
        float kb = kdiff[(size_t)e * K_N + t];
        x[t] = ikp[(size_t)row * K_N + t] * (sigmoidf_(sb) - sigmoidf_(kb)) * ed;
    }
    __syncthreads();

    // h1[t] = tanh(|W1[t,:]| . x + b1[t]),  W1: [256,128]
    {
        const float4* w = (const float4*)(W1 + (size_t)t * 128);
        const float4* xv = (const float4*)x;
        float acc = 0.0f;
#pragma unroll
        for (int j = 0; j < 32; ++j) {
            float4 wv = w[j];
            float4 vv = xv[j];
            acc += fabsf(wv.x) * vv.x + fabsf(wv.y) * vv.y +
                   fabsf(wv.z) * vv.z + fabsf(wv.w) * vv.w;
        }
        h1[t] = tanhf(acc + b1[t]);
    }
    __syncthreads();

    // h2[t] = tanh(|W2[t,:]| . h1 + b2[t]),  W2: [128,256]
    if (t < 128) {
        const float4* w = (const float4*)(W2 + (size_t)t * 256);
        const float4* hv = (const float4*)h1;
        float acc = 0.0f;
#pragma unroll
        for (int j = 0; j < 64; ++j) {
            float4 wv = w[j];
            float4 vv = hv[j];
            acc += fabsf(wv.x) * vv.x + fabsf(wv.y) * vv.y +
                   fabsf(wv.z) * vv.z + fabsf(wv.w) * vv.w;
        }
        h2[t] = acc + b2[t];
    }
    __syncthreads();

    // out = sigmoid(|W3| . tanh(h2) + b3),  W3: [1,128]
    if (t < 64) {
        float acc = fabsf(W3[t]) * tanhf(h2[t]) + fabsf(W3[t + 64]) * tanhf(h2[t + 64]);
#pragma unroll
        for (int off = 32; off > 0; off >>= 1)
            acc += __shfl_down(acc, off);
        if (t == 0) out[row] = sigmoidf_(acc + b3[0]);
    }
}

extern "C" void kernel_launch(void* const* d_in, const int* in_sizes, int n_in,
                              void* d_out, int out_size, void* d_ws, size_t ws_size,
                              hipStream_t stream) {
    const int* stu_id        = (const int*)d_in[0];
    const int* input_ex      = (const int*)d_in[1];
    const float* ikp         = (const float*)d_in[2];
    const int* rows_1        = (const int*)d_in[3];
    const int* cols_1        = (const int*)d_in[4];
    const int* rows_0        = (const int*)d_in[5];
    const int* cols_0        = (const int*)d_in[6];
    const float* vals_ui_1   = (const float*)d_in[7];
    const float* vals_iu_1   = (const float*)d_in[8];
    const float* vals_ui_0   = (const float*)d_in[9];
    const float* vals_iu_0   = (const float*)d_in[10];
    const float* d_i_1       = (const float*)d_in[11];
    const float* d_j_1       = (const float*)d_in[12];
    const float* d_i_0       = (const float*)d_in[13];
    const float* d_j_0       = (const float*)d_in[14];
    const float* student_emb = (const float*)d_in[15];
    const float* exercise_emb= (const float*)d_in[16];
    const float* s_bias      = (const float*)d_in[17];
    const float* e_disc      = (const float*)d_in[18];
    const float* W1          = (const float*)d_in[19];
    const float* b1          = (const float*)d_in[20];
    const float* W2          = (const float*)d_in[21];
    const float* b2          = (const float*)d_in[22];
    const float* W3          = (const float*)d_in[23];
    const float* b3          = (const float*)d_in[24];

    // workspace layout: double-buffered node tables (f32)
    float* statA  = (float*)d_ws;
    float* kdiffA = statA + (size_t)S_N * K_N;
    float* statB  = kdiffA + (size_t)E_N * K_N;
    float* kdiffB = statB + (size_t)S_N * K_N;

    const int sBlocks = (S_N * (K_N / 4) + 255) / 256;  // 6250
    const int eBlocks = (E_N * (K_N / 4) + 255) / 256;  // 2500
    const int edgeBlocks = (int)(((long long)2 * NE_N * 32 + 255) / 256);  // 250000

    // ---- layer 1: old = inputs, new = A ----
    scale_nodes<<<sBlocks, 256, 0, stream>>>((const float4*)student_emb, d_i_1, d_i_0,
                                             (float4*)statA, S_N);
    scale_nodes<<<eBlocks, 256, 0, stream>>>((const float4*)exercise_emb, d_j_1, d_j_0,
                                             (float4*)kdiffA, E_N);
    edge_pass<<<edgeBlocks, 256, 0, stream>>>(student_emb, exercise_emb, statA, kdiffA,
                                              rows_1, cols_1, vals_ui_1, vals_iu_1,
                                              rows_0, cols_0, vals_ui_0, vals_iu_0);

    // ---- layer 2: old = A, new = B ----
    scale_nodes<<<sBlocks, 256, 0, stream>>>((const float4*)statA, d_i_1, d_i_0,
                                             (float4*)statB, S_N);
    scale_nodes<<<eBlocks, 256, 0, stream>>>((const float4*)kdiffA, d_j_1, d_j_0,
                                             (float4*)kdiffB, E_N);
    edge_pass<<<edgeBlocks, 256, 0, stream>>>(statA, kdiffA, statB, kdiffB,
                                              rows_1, cols_1, vals_ui_1, vals_iu_1,
                                              rows_0, cols_0, vals_ui_0, vals_iu_0);

    // ---- prediction ----
    predict<<<B_N, 256, 0, stream>>>(stu_id, input_ex, ikp, statB, kdiffB,
                                     s_bias, e_disc, W1, b1, W2, b2, W3, b3,
                                     (float*)d_out);
}

// Round 2
// 1720.562 us; speedup vs baseline: 8.1262x; 8.1262x over previous
//
#include <hip/hip_runtime.h>

#define S_N 50000
#define E_N 20000
#define K_N 128
#define B_N 16384
#define NE_N 1000000

__device__ __forceinline__ float sigmoidf_(float v) {
    return 1.0f / (1.0f + __expf(-v));
}

// ---- CSR build ----------------------------------------------------------

// count edges per destination node (both graphs merged per side)
__global__ __launch_bounds__(256) void histogram_kernel(
    const int* __restrict__ r1, const int* __restrict__ c1,
    const int* __restrict__ r0, const int* __restrict__ c0,
    int* __restrict__ cntS, int* __restrict__ cntE) {
    int i = blockIdx.x * blockDim.x + threadIdx.x;
    if (i < NE_N) {
        atomicAdd(&cntS[r1[i]], 1);
        atomicAdd(&cntE[c1[i]], 1);
    } else if (i < 2 * NE_N) {
        int j = i - NE_N;
        atomicAdd(&cntS[r0[j]], 1);
        atomicAdd(&cntE[c0[j]], 1);
    }
}

// single-workgroup exclusive scan: off[0..n] and a cursor copy cur[0..n-1]
__global__ __launch_bounds__(1024) void exscan_kernel(
    const int* __restrict__ cnt, int n,
    int* __restrict__ off, int* __restrict__ cur) {
    __shared__ int buf[1024];
    __shared__ int carry_s;
    int t = threadIdx.x;
    if (t == 0) carry_s = 0;
    __syncthreads();
    for (int base = 0; base < n; base += 1024) {
        int idx = base + t;
        int v = (idx < n) ? cnt[idx] : 0;
        buf[t] = v;
        __syncthreads();
        int acc = v;
        for (int d = 1; d < 1024; d <<= 1) {
            int add = (t >= d) ? buf[t - d] : 0;
            __syncthreads();
            acc += add;
            buf[t] = acc;
            __syncthreads();
        }
        int excl = acc - v + carry_s;
        if (idx < n) { off[idx] = excl; cur[idx] = excl; }
        __syncthreads();
        if (t == 1023) carry_s += acc;  // acc here is the chunk total
        __syncthreads();
    }
    if (t == 0) off[n] = carry_s;
}

// scatter edges into CSR buckets: entry = (src_node, weight_bits)
__global__ __launch_bounds__(256) void fill_kernel(
    const int* __restrict__ r1, const int* __restrict__ c1,
    const float* __restrict__ vui1, const float* __restrict__ viu1,
    const int* __restrict__ r0, const int* __restrict__ c0,
    const float* __restrict__ vui0, const float* __restrict__ viu0,
    int* __restrict__ curS, int* __restrict__ curE,
    int2* __restrict__ csrS, int2* __restrict__ csrE) {
    int i = blockIdx.x * blockDim.x + threadIdx.x;
    int r, c; float a, b;
    if (i < NE_N) {
        r = r1[i]; c = c1[i]; a = vui1[i]; b = viu1[i];
    } else if (i < 2 * NE_N) {
        int j = i - NE_N;
        r = r0[j]; c = c0[j]; a = vui0[j]; b = viu0[j];
    } else return;
    int s1 = atomicAdd(&curS[r], 1);
    csrS[s1] = make_int2(c, __float_as_int(a));
    int s2 = atomicAdd(&curE[c], 1);
    csrE[s2] = make_int2(r, __float_as_int(b));
}

// ---- propagation: one wave per destination row, 64 lanes x float2 ------
// dst[w] = self[w]*(dA[w]+dB[w]) + sum_{edges} val * src[src_idx]
__global__ __launch_bounds__(256) void gather_pass(
    const float* __restrict__ src, const float* __restrict__ self,
    const float* __restrict__ dA, const float* __restrict__ dB,
    const int* __restrict__ off, const int2* __restrict__ csr,
    float* __restrict__ dst, int nrow) {
    int w = blockIdx.x * 4 + (threadIdx.x >> 6);
    int lane = threadIdx.x & 63;
    if (w >= nrow) return;
    float d = dA[w] + dB[w];
    float2 sv = ((const float2*)(self + (size_t)w * K_N))[lane];
    float ax = sv.x * d, ay = sv.y * d;
    int i = off[w], end = off[w + 1];
    for (; i + 4 <= end; i += 4) {
        int2 e0 = csr[i], e1 = csr[i + 1], e2 = csr[i + 2], e3 = csr[i + 3];
        float2 s0 = ((const float2*)(src + (size_t)e0.x * K_N))[lane];
        float2 s1 = ((const float2*)(src + (size_t)e1.x * K_N))[lane];
        float2 s2 = ((const float2*)(src + (size_t)e2.x * K_N))[lane];
        float2 s3 = ((const float2*)(src + (size_t)e3.x * K_N))[lane];
        float v0 = __int_as_float(e0.y), v1 = __int_as_float(e1.y);
        float v2 = __int_as_float(e2.y), v3 = __int_as_float(e3.y);
        ax = fmaf(v0, s0.x, ax); ay = fmaf(v0, s0.y, ay);
        ax = fmaf(v1, s1.x, ax); ay = fmaf(v1, s1.y, ay);
        ax = fmaf(v2, s2.x, ax); ay = fmaf(v2, s2.y, ay);
        ax = fmaf(v3, s3.x, ax); ay = fmaf(v3, s3.y, ay);
    }
    for (; i < end; ++i) {
        int2 e = csr[i];
        float2 s = ((const float2*)(src + (size_t)e.x * K_N))[lane];
        float v = __int_as_float(e.y);
        ax = fmaf(v, s.x, ax); ay = fmaf(v, s.y, ay);
    }
    ((float2*)(dst + (size_t)w * K_N))[lane] = make_float2(ax, ay);
}

// ---- prediction MLP -----------------------------------------------------
__global__ __launch_bounds__(256) void predict(
    const int* __restrict__ stu_id, const int* __restrict__ ex_id,
    const float* __restrict__ ikp,
    const float* __restrict__ stat, const float* __restrict__ kdiff,
    const float* __restrict__ s_bias, const float* __restrict__ e_disc,
    const float* __restrict__ W1, const float* __restrict__ b1,
    const float* __restrict__ W2, const float* __restrict__ b2,
    const float* __restrict__ W3, const float* __restrict__ b3,
    float* __restrict__ out) {
    __shared__ __align__(16) float x[128];
    __shared__ __align__(16) float h1[256];
    __shared__ __align__(16) float h2[128];

    int row = blockIdx.x;
    int t = threadIdx.x;
    int s = stu_id[row];
    int e = ex_id[row];
    float ed = sigmoidf_(e_disc[e]);

    if (t < 128) {
        float sb = stat[(size_t)s * K_N + t] + s_bias[s];
        float kb = kdiff[(size_t)e * K_N + t];
        x[t] = ikp[(size_t)row * K_N + t] * (sigmoidf_(sb) - sigmoidf_(kb)) * ed;
    }
    __syncthreads();

    {
        const float4* w = (const float4*)(W1 + (size_t)t * 128);
        const float4* xv = (const float4*)x;
        float acc = 0.0f;
#pragma unroll
        for (int j = 0; j < 32; ++j) {
            float4 wv = w[j];
            float4 vv = xv[j];
            acc += fabsf(wv.x) * vv.x + fabsf(wv.y) * vv.y +
                   fabsf(wv.z) * vv.z + fabsf(wv.w) * vv.w;
        }
        h1[t] = tanhf(acc + b1[t]);
    }
    __syncthreads();

    if (t < 128) {
        const float4* w = (const float4*)(W2 + (size_t)t * 256);
        const float4* hv = (const float4*)h1;
        float acc = 0.0f;
#pragma unroll
        for (int j = 0; j < 64; ++j) {
            float4 wv = w[j];
            float4 vv = hv[j];
            acc += fabsf(wv.x) * vv.x + fabsf(wv.y) * vv.y +
                   fabsf(wv.z) * vv.z + fabsf(wv.w) * vv.w;
        }
        h2[t] = acc + b2[t];
    }
    __syncthreads();

    if (t < 64) {
        float acc = fabsf(W3[t]) * tanhf(h2[t]) + fabsf(W3[t + 64]) * tanhf(h2[t + 64]);
#pragma unroll
        for (int off = 32; off > 0; off >>= 1)
            acc += __shfl_down(acc, off);
        if (t == 0) out[row] = sigmoidf_(acc + b3[0]);
    }
}

extern "C" void kernel_launch(void* const* d_in, const int* in_sizes, int n_in,
                              void* d_out, int out_size, void* d_ws, size_t ws_size,
                              hipStream_t stream) {
    const int* stu_id        = (const int*)d_in[0];
    const int* input_ex      = (const int*)d_in[1];
    const float* ikp         = (const float*)d_in[2];
    const int* rows_1        = (const int*)d_in[3];
    const int* cols_1        = (const int*)d_in[4];
    const int* rows_0        = (const int*)d_in[5];
    const int* cols_0        = (const int*)d_in[6];
    const float* vals_ui_1   = (const float*)d_in[7];
    const float* vals_iu_1   = (const float*)d_in[8];
    const float* vals_ui_0   = (const float*)d_in[9];
    const float* vals_iu_0   = (const float*)d_in[10];
    const float* d_i_1       = (const float*)d_in[11];
    const float* d_j_1       = (const float*)d_in[12];
    const float* d_i_0       = (const float*)d_in[13];
    const float* d_j_0       = (const float*)d_in[14];
    const float* student_emb = (const float*)d_in[15];
    const float* exercise_emb= (const float*)d_in[16];
    const float* s_bias      = (const float*)d_in[17];
    const float* e_disc      = (const float*)d_in[18];
    const float* W1          = (const float*)d_in[19];
    const float* b1          = (const float*)d_in[20];
    const float* W2          = (const float*)d_in[21];
    const float* b2          = (const float*)d_in[22];
    const float* W3          = (const float*)d_in[23];
    const float* b3          = (const float*)d_in[24];

    // ---- workspace layout ----
    char* p = (char*)d_ws;
    float* statA  = (float*)p; p += (size_t)S_N * K_N * 4;
    float* kdiffA = (float*)p; p += (size_t)E_N * K_N * 4;
    float* statB  = (float*)p; p += (size_t)S_N * K_N * 4;
    float* kdiffB = (float*)p; p += (size_t)E_N * K_N * 4;
    int2* csrS    = (int2*)p;  p += (size_t)2 * NE_N * 8;
    int2* csrE    = (int2*)p;  p += (size_t)2 * NE_N * 8;
    int* cntS     = (int*)p;   p += (size_t)S_N * 4;
    int* cntE     = (int*)p;   p += (size_t)E_N * 4;
    int* offS     = (int*)p;   p += (size_t)(S_N + 1) * 4;
    int* offE     = (int*)p;   p += (size_t)(E_N + 1) * 4;
    int* curS     = (int*)p;   p += (size_t)S_N * 4;
    int* curE     = (int*)p;   p += (size_t)E_N * 4;

    // ---- CSR build ----
    hipMemsetAsync(cntS, 0, (size_t)S_N * 4, stream);
    hipMemsetAsync(cntE, 0, (size_t)E_N * 4, stream);
    const int edgeThreads = (2 * NE_N + 255) / 256;
    histogram_kernel<<<edgeThreads, 256, 0, stream>>>(rows_1, cols_1, rows_0, cols_0, cntS, cntE);
    exscan_kernel<<<1, 1024, 0, stream>>>(cntS, S_N, offS, curS);
    exscan_kernel<<<1, 1024, 0, stream>>>(cntE, E_N, offE, curE);
    fill_kernel<<<edgeThreads, 256, 0, stream>>>(rows_1, cols_1, vals_ui_1, vals_iu_1,
                                                 rows_0, cols_0, vals_ui_0, vals_iu_0,
                                                 curS, curE, csrS, csrE);

    const int sGrid = (S_N + 3) / 4;
    const int eGrid = (E_N + 3) / 4;

    // ---- layer 1: inputs -> A ----
    gather_pass<<<sGrid, 256, 0, stream>>>(exercise_emb, student_emb, d_i_1, d_i_0,
                                           offS, csrS, statA, S_N);
    gather_pass<<<eGrid, 256, 0, stream>>>(student_emb, exercise_emb, d_j_1, d_j_0,
                                           offE, csrE, kdiffA, E_N);

    // ---- layer 2: A -> B ----
    gather_pass<<<sGrid, 256, 0, stream>>>(kdiffA, statA, d_i_1, d_i_0,
                                           offS, csrS, statB, S_N);
    gather_pass<<<eGrid, 256, 0, stream>>>(statA, kdiffA, d_j_1, d_j_0,
                                           offE, csrE, kdiffB, E_N);

    // ---- prediction ----
    predict<<<B_N, 256, 0, stream>>>(stu_id, input_ex, ikp, statB, kdiffB,
                                     s_bias, e_disc, W1, b1, W2, b2, W3, b3,
                                     (float*)d_out);
}

// Round 3
// 1386.121 us; speedup vs baseline: 10.0869x; 1.2413x over previous
//
#include <hip/hip_runtime.h>

#define S_N 50000
#define E_N 20000
#define K_N 128
#define B_N 16384
#define NE_N 1000000

__device__ __forceinline__ float sigmoidf_(float v) {
    return 1.0f / (1.0f + __expf(-v));
}
__device__ __forceinline__ float tanh_fast(float v) {
    float e = __expf(2.0f * v);
    return 1.0f - 2.0f / (e + 1.0f);
}

// ---- CSR build ----------------------------------------------------------

__global__ __launch_bounds__(256) void histogram_kernel(
    const int* __restrict__ r1, const int* __restrict__ c1,
    const int* __restrict__ r0, const int* __restrict__ c0,
    int* __restrict__ cntS, int* __restrict__ cntE) {
    int i = blockIdx.x * blockDim.x + threadIdx.x;
    if (i < NE_N) {
        atomicAdd(&cntS[r1[i]], 1);
        atomicAdd(&cntE[c1[i]], 1);
    } else if (i < 2 * NE_N) {
        int j = i - NE_N;
        atomicAdd(&cntS[r0[j]], 1);
        atomicAdd(&cntE[c0[j]], 1);
    }
}

__global__ __launch_bounds__(1024) void exscan_kernel(
    const int* __restrict__ cnt, int n,
    int* __restrict__ off, int* __restrict__ cur) {
    __shared__ int buf[1024];
    __shared__ int carry_s;
    int t = threadIdx.x;
    if (t == 0) carry_s = 0;
    __syncthreads();
    for (int base = 0; base < n; base += 1024) {
        int idx = base + t;
        int v = (idx < n) ? cnt[idx] : 0;
        buf[t] = v;
        __syncthreads();
        int acc = v;
        for (int d = 1; d < 1024; d <<= 1) {
            int add = (t >= d) ? buf[t - d] : 0;
            __syncthreads();
            acc += add;
            buf[t] = acc;
            __syncthreads();
        }
        int excl = acc - v + carry_s;
        if (idx < n) { off[idx] = excl; cur[idx] = excl; }
        __syncthreads();
        if (t == 1023) carry_s += acc;
        __syncthreads();
    }
    if (t == 0) off[n] = carry_s;
}

__global__ __launch_bounds__(256) void fill_kernel(
    const int* __restrict__ r1, const int* __restrict__ c1,
    const float* __restrict__ vui1, const float* __restrict__ viu1,
    const int* __restrict__ r0, const int* __restrict__ c0,
    const float* __restrict__ vui0, const float* __restrict__ viu0,
    int* __restrict__ curS, int* __restrict__ curE,
    int2* __restrict__ csrS, int2* __restrict__ csrE) {
    int i = blockIdx.x * blockDim.x + threadIdx.x;
    int r, c; float a, b;
    if (i < NE_N) {
        r = r1[i]; c = c1[i]; a = vui1[i]; b = viu1[i];
    } else if (i < 2 * NE_N) {
        int j = i - NE_N;
        r = r0[j]; c = c0[j]; a = vui0[j]; b = viu0[j];
    } else return;
    int s1 = atomicAdd(&curS[r], 1);
    csrS[s1] = make_int2(c, __float_as_int(a));
    int s2 = atomicAdd(&curE[c], 1);
    csrE[s2] = make_int2(r, __float_as_int(b));
}

// ---- propagation: one wave per destination row, 64 lanes x float2 ------
__global__ __launch_bounds__(256) void gather_pass(
    const float* __restrict__ src, const float* __restrict__ self,
    const float* __restrict__ dA, const float* __restrict__ dB,
    const int* __restrict__ off, const int2* __restrict__ csr,
    float* __restrict__ dst, int nrow) {
    int w = blockIdx.x * 4 + (threadIdx.x >> 6);
    int lane = threadIdx.x & 63;
    if (w >= nrow) return;
    float d = dA[w] + dB[w];
    float2 sv = ((const float2*)(self + (size_t)w * K_N))[lane];
    float ax = sv.x * d, ay = sv.y * d;
    int i = off[w], end = off[w + 1];
    for (; i + 4 <= end; i += 4) {
        int2 e0 = csr[i], e1 = csr[i + 1], e2 = csr[i + 2], e3 = csr[i + 3];
        float2 s0 = ((const float2*)(src + (size_t)e0.x * K_N))[lane];
        float2 s1 = ((const float2*)(src + (size_t)e1.x * K_N))[lane];
        float2 s2 = ((const float2*)(src + (size_t)e2.x * K_N))[lane];
        float2 s3 = ((const float2*)(src + (size_t)e3.x * K_N))[lane];
        float v0 = __int_as_float(e0.y), v1 = __int_as_float(e1.y);
        float v2 = __int_as_float(e2.y), v3 = __int_as_float(e3.y);
        ax = fmaf(v0, s0.x, ax); ay = fmaf(v0, s0.y, ay);
        ax = fmaf(v1, s1.x, ax); ay = fmaf(v1, s1.y, ay);
        ax = fmaf(v2, s2.x, ax); ay = fmaf(v2, s2.y, ay);
        ax = fmaf(v3, s3.x, ax); ay = fmaf(v3, s3.y, ay);
    }
    for (; i < end; ++i) {
        int2 e = csr[i];
        float2 s = ((const float2*)(src + (size_t)e.x * K_N))[lane];
        float v = __int_as_float(e.y);
        ax = fmaf(v, s.x, ax); ay = fmaf(v, s.y, ay);
    }
    ((float2*)(dst + (size_t)w * K_N))[lane] = make_float2(ax, ay);
}

// ---- prediction MLP: 64 batch rows per block, 512 threads ---------------
// lane (0..63) = row within tile; wave (0..7) = column block.
// Weight indices are wave-uniform -> scalar loads; |W| via abs modifier.
#define XS 133   // x / h2 LDS row stride (odd -> conflict-free)
#define HS 261   // h1 LDS row stride

__global__ __launch_bounds__(512) void predict_tiled(
    const int* __restrict__ stu_id, const int* __restrict__ ex_id,
    const float* __restrict__ ikp,
    const float* __restrict__ stat, const float* __restrict__ kdiff,
    const float* __restrict__ s_bias, const float* __restrict__ e_disc,
    const float* __restrict__ W1, const float* __restrict__ b1,
    const float* __restrict__ W2, const float* __restrict__ b2,
    const float* __restrict__ W3, const float* __restrict__ b3,
    float* __restrict__ out) {
    __shared__ float xbuf[64 * XS];    // x, later reused as h2 (pre-tanh)
    __shared__ float h1buf[64 * HS];
    __shared__ float sb_sh[64];
    __shared__ float ed_sh[64];
    __shared__ int sid_sh[64];
    __shared__ int eid_sh[64];

    const int t = threadIdx.x;
    const int r0 = blockIdx.x * 64;
    const int lane = t & 63;
    const int w = __builtin_amdgcn_readfirstlane(t >> 6);

    // per-row scalars
    if (t < 64) {
        int row = r0 + t;
        int s = stu_id[row];
        int e = ex_id[row];
        sid_sh[t] = s;
        eid_sh[t] = e;
        sb_sh[t] = s_bias[s];
        ed_sh[t] = sigmoidf_(e_disc[e]);
    }
    __syncthreads();

    // ---- phase A: feature x[r][k] ----
#pragma unroll
    for (int it = 0; it < 16; ++it) {
        int i = it * 512 + t;            // 0..8191
        int r = i >> 7;
        int k = i & 127;
        int row = r0 + r;
        int s = sid_sh[r];
        int e = eid_sh[r];
        float sv = stat[(size_t)s * K_N + k] + sb_sh[r];
        float kv = kdiff[(size_t)e * K_N + k];
        xbuf[r * XS + k] = ikp[(size_t)row * K_N + k] *
                           (sigmoidf_(sv) - sigmoidf_(kv)) * ed_sh[r];
    }
    __syncthreads();

    // ---- layer 1: h1[r][c] = tanh(|W1[c,:]| . x[r,:] + b1[c]) ----
    {
        const int c0 = w * 32;
        float acc[32];
#pragma unroll
        for (int c = 0; c < 32; ++c) acc[c] = 0.0f;
        for (int k0 = 0; k0 < 128; k0 += 16) {
            float xr[16];
#pragma unroll
            for (int j = 0; j < 16; ++j) xr[j] = xbuf[lane * XS + k0 + j];
#pragma unroll
            for (int c = 0; c < 32; ++c) {
                const float* wrow = W1 + (size_t)(c0 + c) * 128 + k0;
#pragma unroll
                for (int j = 0; j < 16; ++j)
                    acc[c] = fmaf(fabsf(wrow[j]), xr[j], acc[c]);
            }
        }
#pragma unroll
        for (int c = 0; c < 32; ++c)
            h1buf[lane * HS + c0 + c] = tanh_fast(acc[c] + b1[c0 + c]);
    }
    __syncthreads();

    // ---- layer 2: h2[r][c] = |W2[c,:]| . h1[r,:] + b2[c]  (pre-tanh) ----
    {
        const int c0 = w * 16;
        float acc[16];
#pragma unroll
        for (int c = 0; c < 16; ++c) acc[c] = 0.0f;
        for (int k0 = 0; k0 < 256; k0 += 16) {
            float hr[16];
#pragma unroll
            for (int j = 0; j < 16; ++j) hr[j] = h1buf[lane * HS + k0 + j];
#pragma unroll
            for (int c = 0; c < 16; ++c) {
                const float* wrow = W2 + (size_t)(c0 + c) * 256 + k0;
#pragma unroll
                for (int j = 0; j < 16; ++j)
                    acc[c] = fmaf(fabsf(wrow[j]), hr[j], acc[c]);
            }
        }
        __syncthreads();  // xbuf (x) is dead; safe to overwrite as h2
#pragma unroll
        for (int c = 0; c < 16; ++c)
            xbuf[lane * XS + c0 + c] = acc[c] + b2[c0 + c];
    }
    __syncthreads();

    // ---- layer 3: out[r] = sigmoid(sum_c |W3[c]| tanh(h2[r][c]) + b3) ----
    {
        int sub = lane & 7;              // c phase
        int rr = w * 8 + (lane >> 3);    // row 0..63
        float acc3 = 0.0f;
#pragma unroll
        for (int j = 0; j < 16; ++j) {
            int c = sub + j * 8;
            acc3 += fabsf(W3[c]) * tanh_fast(xbuf[rr * XS + c]);
        }
        acc3 += __shfl_down(acc3, 4, 8);
        acc3 += __shfl_down(acc3, 2, 8);
        acc3 += __shfl_down(acc3, 1, 8);
        if (sub == 0) out[r0 + rr] = sigmoidf_(acc3 + b3[0]);
    }
}

extern "C" void kernel_launch(void* const* d_in, const int* in_sizes, int n_in,
                              void* d_out, int out_size, void* d_ws, size_t ws_size,
                              hipStream_t stream) {
    const int* stu_id        = (const int*)d_in[0];
    const int* input_ex      = (const int*)d_in[1];
    const float* ikp         = (const float*)d_in[2];
    const int* rows_1        = (const int*)d_in[3];
    const int* cols_1        = (const int*)d_in[4];
    const int* rows_0        = (const int*)d_in[5];
    const int* cols_0        = (const int*)d_in[6];
    const float* vals_ui_1   = (const float*)d_in[7];
    const float* vals_iu_1   = (const float*)d_in[8];
    const float* vals_ui_0   = (const float*)d_in[9];
    const float* vals_iu_0   = (const float*)d_in[10];
    const float* d_i_1       = (const float*)d_in[11];
    const float* d_j_1       = (const float*)d_in[12];
    const float* d_i_0       = (const float*)d_in[13];
    const float* d_j_0       = (const float*)d_in[14];
    const float* student_emb = (const float*)d_in[15];
    const float* exercise_emb= (const float*)d_in[16];
    const float* s_bias      = (const float*)d_in[17];
    const float* e_disc      = (const float*)d_in[18];
    const float* W1          = (const float*)d_in[19];
    const float* b1          = (const float*)d_in[20];
    const float* W2          = (const float*)d_in[21];
    const float* b2          = (const float*)d_in[22];
    const float* W3          = (const float*)d_in[23];
    const float* b3          = (const float*)d_in[24];

    // ---- workspace layout ----
    char* p = (char*)d_ws;
    float* statA  = (float*)p; p += (size_t)S_N * K_N * 4;
    float* kdiffA = (float*)p; p += (size_t)E_N * K_N * 4;
    float* statB  = (float*)p; p += (size_t)S_N * K_N * 4;
    float* kdiffB = (float*)p; p += (size_t)E_N * K_N * 4;
    int2* csrS    = (int2*)p;  p += (size_t)2 * NE_N * 8;
    int2* csrE    = (int2*)p;  p += (size_t)2 * NE_N * 8;
    int* cntS     = (int*)p;   p += (size_t)S_N * 4;
    int* cntE     = (int*)p;   p += (size_t)E_N * 4;
    int* offS     = (int*)p;   p += (size_t)(S_N + 1) * 4;
    int* offE     = (int*)p;   p += (size_t)(E_N + 1) * 4;
    int* curS     = (int*)p;   p += (size_t)S_N * 4;
    int* curE     = (int*)p;   p += (size_t)E_N * 4;

    // ---- CSR build ----
    hipMemsetAsync(cntS, 0, (size_t)S_N * 4, stream);
    hipMemsetAsync(cntE, 0, (size_t)E_N * 4, stream);
    const int edgeThreads = (2 * NE_N + 255) / 256;
    histogram_kernel<<<edgeThreads, 256, 0, stream>>>(rows_1, cols_1, rows_0, cols_0, cntS, cntE);
    exscan_kernel<<<1, 1024, 0, stream>>>(cntS, S_N, offS, curS);
    exscan_kernel<<<1, 1024, 0, stream>>>(cntE, E_N, offE, curE);
    fill_kernel<<<edgeThreads, 256, 0, stream>>>(rows_1, cols_1, vals_ui_1, vals_iu_1,
                                                 rows_0, cols_0, vals_ui_0, vals_iu_0,
                                                 curS, curE, csrS, csrE);

    const int sGrid = (S_N + 3) / 4;
    const int eGrid = (E_N + 3) / 4;

    // ---- layer 1: inputs -> A ----
    gather_pass<<<sGrid, 256, 0, stream>>>(exercise_emb, student_emb, d_i_1, d_i_0,
                                           offS, csrS, statA, S_N);
    gather_pass<<<eGrid, 256, 0, stream>>>(student_emb, exercise_emb, d_j_1, d_j_0,
                                           offE, csrE, kdiffA, E_N);

    // ---- layer 2: A -> B ----
    gather_pass<<<sGrid, 256, 0, stream>>>(kdiffA, statA, d_i_1, d_i_0,
                                           offS, csrS, statB, S_N);
    gather_pass<<<eGrid, 256, 0, stream>>>(statA, kdiffA, d_j_1, d_j_0,
                                           offE, csrE, kdiffB, E_N);

    // ---- prediction ----
    predict_tiled<<<B_N / 64, 512, 0, stream>>>(stu_id, input_ex, ikp, statB, kdiffB,
                                                s_bias, e_disc, W1, b1, W2, b2, W3, b3,
                                                (float*)d_out);
}

// Round 4
// 1112.930 us; speedup vs baseline: 12.5629x; 1.2455x over previous
//
#include <hip/hip_runtime.h>

#define S_N 50000
#define E_N 20000
#define K_N 128
#define B_N 16384
#define NE_N 1000000

#define S_PER_XCD 6250   // ceil(S_N/8)
#define E_PER_XCD 2500   // ceil(E_N/8)

__device__ __forceinline__ float sigmoidf_(float v) {
    return 1.0f / (1.0f + __expf(-v));
}
__device__ __forceinline__ float tanh_fast(float v) {
    float e = __expf(2.0f * v);
    return 1.0f - 2.0f / (e + 1.0f);
}

// ---- CSR build ----------------------------------------------------------

__global__ __launch_bounds__(256) void histogram_kernel(
    const int* __restrict__ r1, const int* __restrict__ c1,
    const int* __restrict__ r0, const int* __restrict__ c0,
    int* __restrict__ cntS, int* __restrict__ cntE) {
    int i = blockIdx.x * blockDim.x + threadIdx.x;
    if (i < NE_N) {
        atomicAdd(&cntS[r1[i]], 1);
        atomicAdd(&cntE[c1[i]], 1);
    } else if (i < 2 * NE_N) {
        int j = i - NE_N;
        atomicAdd(&cntS[r0[j]], 1);
        atomicAdd(&cntE[c0[j]], 1);
    }
}

// wave-shuffle exclusive scan, single workgroup of 1024 threads
__global__ __launch_bounds__(1024) void exscan_kernel(
    const int* __restrict__ cnt, int n,
    int* __restrict__ off, int* __restrict__ cur) {
    __shared__ int wsum[16];
    __shared__ int carry_s;
    const int t = threadIdx.x;
    const int lane = t & 63;
    const int wid = t >> 6;
    if (t == 0) carry_s = 0;
    __syncthreads();
    for (int base = 0; base < n; base += 1024) {
        int idx = base + t;
        int v = (idx < n) ? cnt[idx] : 0;
        // inclusive scan within wave
        int s = v;
#pragma unroll
        for (int d = 1; d < 64; d <<= 1) {
            int o = __shfl_up(s, d);
            if (lane >= d) s += o;
        }
        if (lane == 63) wsum[wid] = s;
        __syncthreads();
        if (wid == 0) {
            int ws = (lane < 16) ? wsum[lane] : 0;
#pragma unroll
            for (int d = 1; d < 16; d <<= 1) {
                int o = __shfl_up(ws, d);
                if (lane >= d) ws += o;
            }
            if (lane < 16) wsum[lane] = ws;   // inclusive over waves
        }
        __syncthreads();
        int waveoff = (wid == 0) ? 0 : wsum[wid - 1];
        int excl = carry_s + waveoff + s - v;
        if (idx < n) { off[idx] = excl; cur[idx] = excl; }
        __syncthreads();
        if (t == 1023) carry_s += wsum[15];
        // next iteration's first __syncthreads orders this vs. readers
    }
    __syncthreads();
    if (t == 0) off[n] = carry_s;
}

// XCD-partitioned scatter: block b targets XCD x=b&7 (dispatch heuristic);
// it scans edge chunk b>>3 and writes only edges whose DEST node falls in
// XCD x's range, so each XCD's CSR window (~3 MB) stays resident in its L2
// and lines are fully assembled before writeback. Each edge matches exactly
// one x per side -> written exactly once regardless of actual block->XCD map.
__global__ __launch_bounds__(256) void fill_kernel_xcd(
    const int* __restrict__ r1, const int* __restrict__ c1,
    const float* __restrict__ vui1, const float* __restrict__ viu1,
    const int* __restrict__ r0, const int* __restrict__ c0,
    const float* __restrict__ vui0, const float* __restrict__ viu0,
    int* __restrict__ curS, int* __restrict__ curE,
    int2* __restrict__ csrS, int2* __restrict__ csrE) {
    const int x = blockIdx.x & 7;
    const int chunk = blockIdx.x >> 3;
    const int i = chunk * 256 + threadIdx.x;
    if (i >= 2 * NE_N) return;
    const int sLo = x * S_PER_XCD, sHi = sLo + S_PER_XCD;
    const int eLo = x * E_PER_XCD, eHi = eLo + E_PER_XCD;
    int r, c; float a, b;
    if (i < NE_N) {
        r = r1[i]; c = c1[i]; a = vui1[i]; b = viu1[i];
    } else {
        int j = i - NE_N;
        r = r0[j]; c = c0[j]; a = vui0[j]; b = viu0[j];
    }
    if (r >= sLo && r < sHi) {
        int s = atomicAdd(&curS[r], 1);
        csrS[s] = make_int2(c, __float_as_int(a));
    }
    if (c >= eLo && c < eHi) {
        int s = atomicAdd(&curE[c], 1);
        csrE[s] = make_int2(r, __float_as_int(b));
    }
}

// mark nodes referenced by the batch (for layer-2 row skipping)
__global__ __launch_bounds__(256) void mark_needed(
    const int* __restrict__ ids, int n, unsigned* __restrict__ mask) {
    int i = blockIdx.x * blockDim.x + threadIdx.x;
    if (i < n) {
        int v = ids[i];
        atomicOr(&mask[v >> 5], 1u << (v & 31));
    }
}

// ---- propagation: one wave per destination row, 64 lanes x float2 ------
// need==nullptr -> compute all rows; else skip rows not in the bitmap.
__global__ __launch_bounds__(256) void gather_pass(
    const float* __restrict__ src, const float* __restrict__ self,
    const float* __restrict__ dA, const float* __restrict__ dB,
    const int* __restrict__ off, const int2* __restrict__ csr,
    const unsigned* __restrict__ need,
    float* __restrict__ dst, int nrow) {
    int w = blockIdx.x * 4 + (threadIdx.x >> 6);
    int lane = threadIdx.x & 63;
    if (w >= nrow) return;
    if (need && !((need[w >> 5] >> (w & 31)) & 1u)) return;
    float d = dA[w] + dB[w];
    float2 sv = ((const float2*)(self + (size_t)w * K_N))[lane];
    float ax = sv.x * d, ay = sv.y * d;
    int i = off[w], end = off[w + 1];
    for (; i + 4 <= end; i += 4) {
        int2 e0 = csr[i], e1 = csr[i + 1], e2 = csr[i + 2], e3 = csr[i + 3];
        float2 s0 = ((const float2*)(src + (size_t)e0.x * K_N))[lane];
        float2 s1 = ((const float2*)(src + (size_t)e1.x * K_N))[lane];
        float2 s2 = ((const float2*)(src + (size_t)e2.x * K_N))[lane];
        float2 s3 = ((const float2*)(src + (size_t)e3.x * K_N))[lane];
        float v0 = __int_as_float(e0.y), v1 = __int_as_float(e1.y);
        float v2 = __int_as_float(e2.y), v3 = __int_as_float(e3.y);
        ax = fmaf(v0, s0.x, ax); ay = fmaf(v0, s0.y, ay);
        ax = fmaf(v1, s1.x, ax); ay = fmaf(v1, s1.y, ay);
        ax = fmaf(v2, s2.x, ax); ay = fmaf(v2, s2.y, ay);
        ax = fmaf(v3, s3.x, ax); ay = fmaf(v3, s3.y, ay);
    }
    for (; i < end; ++i) {
        int2 e = csr[i];
        float2 s = ((const float2*)(src + (size_t)e.x * K_N))[lane];
        float v = __int_as_float(e.y);
        ax = fmaf(v, s.x, ax); ay = fmaf(v, s.y, ay);
    }
    ((float2*)(dst + (size_t)w * K_N))[lane] = make_float2(ax, ay);
}

// ---- prediction MLP: 64 batch rows per block, 512 threads ---------------
#define XS 133   // x / h2 LDS row stride (odd -> conflict-free)
#define HS 261   // h1 LDS row stride

__global__ __launch_bounds__(512) void predict_tiled(
    const int* __restrict__ stu_id, const int* __restrict__ ex_id,
    const float* __restrict__ ikp,
    const float* __restrict__ stat, const float* __restrict__ kdiff,
    const float* __restrict__ s_bias, const float* __restrict__ e_disc,
    const float* __restrict__ W1, const float* __restrict__ b1,
    const float* __restrict__ W2, const float* __restrict__ b2,
    const float* __restrict__ W3, const float* __restrict__ b3,
    float* __restrict__ out) {
    __shared__ float xbuf[64 * XS];    // x, later reused as h2 (pre-tanh)
    __shared__ float h1buf[64 * HS];
    __shared__ float sb_sh[64];
    __shared__ float ed_sh[64];
    __shared__ int sid_sh[64];
    __shared__ int eid_sh[64];

    const int t = threadIdx.x;
    const int r0 = blockIdx.x * 64;
    const int lane = t & 63;
    const int w = __builtin_amdgcn_readfirstlane(t >> 6);

    if (t < 64) {
        int row = r0 + t;
        int s = stu_id[row];
        int e = ex_id[row];
        sid_sh[t] = s;
        eid_sh[t] = e;
        sb_sh[t] = s_bias[s];
        ed_sh[t] = sigmoidf_(e_disc[e]);
    }
    __syncthreads();

#pragma unroll
    for (int it = 0; it < 16; ++it) {
        int i = it * 512 + t;
        int r = i >> 7;
        int k = i & 127;
        int row = r0 + r;
        int s = sid_sh[r];
        int e = eid_sh[r];
        float sv = stat[(size_t)s * K_N + k] + sb_sh[r];
        float kv = kdiff[(size_t)e * K_N + k];
        xbuf[r * XS + k] = ikp[(size_t)row * K_N + k] *
                           (sigmoidf_(sv) - sigmoidf_(kv)) * ed_sh[r];
    }
    __syncthreads();

    {
        const int c0 = w * 32;
        float acc[32];
#pragma unroll
        for (int c = 0; c < 32; ++c) acc[c] = 0.0f;
        for (int k0 = 0; k0 < 128; k0 += 16) {
            float xr[16];
#pragma unroll
            for (int j = 0; j < 16; ++j) xr[j] = xbuf[lane * XS + k0 + j];
#pragma unroll
            for (int c = 0; c < 32; ++c) {
                const float* wrow = W1 + (size_t)(c0 + c) * 128 + k0;
#pragma unroll
                for (int j = 0; j < 16; ++j)
                    acc[c] = fmaf(fabsf(wrow[j]), xr[j], acc[c]);
            }
        }
#pragma unroll
        for (int c = 0; c < 32; ++c)
            h1buf[lane * HS + c0 + c] = tanh_fast(acc[c] + b1[c0 + c]);
    }
    __syncthreads();

    {
        const int c0 = w * 16;
        float acc[16];
#pragma unroll
        for (int c = 0; c < 16; ++c) acc[c] = 0.0f;
        for (int k0 = 0; k0 < 256; k0 += 16) {
            float hr[16];
#pragma unroll
            for (int j = 0; j < 16; ++j) hr[j] = h1buf[lane * HS + k0 + j];
#pragma unroll
            for (int c = 0; c < 16; ++c) {
                const float* wrow = W2 + (size_t)(c0 + c) * 256 + k0;
#pragma unroll
                for (int j = 0; j < 16; ++j)
                    acc[c] = fmaf(fabsf(wrow[j]), hr[j], acc[c]);
            }
        }
        __syncthreads();
#pragma unroll
        for (int c = 0; c < 16; ++c)
            xbuf[lane * XS + c0 + c] = acc[c] + b2[c0 + c];
    }
    __syncthreads();

    {
        int sub = lane & 7;
        int rr = w * 8 + (lane >> 3);
        float acc3 = 0.0f;
#pragma unroll
        for (int j = 0; j < 16; ++j) {
            int c = sub + j * 8;
            acc3 += fabsf(W3[c]) * tanh_fast(xbuf[rr * XS + c]);
        }
        acc3 += __shfl_down(acc3, 4, 8);
        acc3 += __shfl_down(acc3, 2, 8);
        acc3 += __shfl_down(acc3, 1, 8);
        if (sub == 0) out[r0 + rr] = sigmoidf_(acc3 + b3[0]);
    }
}

extern "C" void kernel_launch(void* const* d_in, const int* in_sizes, int n_in,
                              void* d_out, int out_size, void* d_ws, size_t ws_size,
                              hipStream_t stream) {
    const int* stu_id        = (const int*)d_in[0];
    const int* input_ex      = (const int*)d_in[1];
    const float* ikp         = (const float*)d_in[2];
    const int* rows_1        = (const int*)d_in[3];
    const int* cols_1        = (const int*)d_in[4];
    const int* rows_0        = (const int*)d_in[5];
    const int* cols_0        = (const int*)d_in[6];
    const float* vals_ui_1   = (const float*)d_in[7];
    const float* vals_iu_1   = (const float*)d_in[8];
    const float* vals_ui_0   = (const float*)d_in[9];
    const float* vals_iu_0   = (const float*)d_in[10];
    const float* d_i_1       = (const float*)d_in[11];
    const float* d_j_1       = (const float*)d_in[12];
    const float* d_i_0       = (const float*)d_in[13];
    const float* d_j_0       = (const float*)d_in[14];
    const float* student_emb = (const float*)d_in[15];
    const float* exercise_emb= (const float*)d_in[16];
    const float* s_bias      = (const float*)d_in[17];
    const float* e_disc      = (const float*)d_in[18];
    const float* W1          = (const float*)d_in[19];
    const float* b1          = (const float*)d_in[20];
    const float* W2          = (const float*)d_in[21];
    const float* b2          = (const float*)d_in[22];
    const float* W3          = (const float*)d_in[23];
    const float* b3          = (const float*)d_in[24];

    // ---- workspace layout ----
    char* p = (char*)d_ws;
    float* statA  = (float*)p; p += (size_t)S_N * K_N * 4;
    float* kdiffA = (float*)p; p += (size_t)E_N * K_N * 4;
    float* statB  = (float*)p; p += (size_t)S_N * K_N * 4;
    float* kdiffB = (float*)p; p += (size_t)E_N * K_N * 4;
    int2* csrS    = (int2*)p;  p += (size_t)2 * NE_N * 8;
    int2* csrE    = (int2*)p;  p += (size_t)2 * NE_N * 8;
    int* cntS     = (int*)p;   p += (size_t)S_N * 4;
    int* cntE     = (int*)p;   p += (size_t)E_N * 4;
    int* offS     = (int*)p;   p += (size_t)(S_N + 1) * 4;
    int* offE     = (int*)p;   p += (size_t)(E_N + 1) * 4;
    int* curS     = (int*)p;   p += (size_t)S_N * 4;
    int* curE     = (int*)p;   p += (size_t)E_N * 4;
    unsigned* maskS = (unsigned*)p; p += 2048 * 4;
    unsigned* maskE = (unsigned*)p; p += 1024 * 4;

    // ---- zero-init counters and masks ----
    hipMemsetAsync(cntS, 0, (size_t)S_N * 4, stream);
    hipMemsetAsync(cntE, 0, (size_t)E_N * 4, stream);
    hipMemsetAsync(maskS, 0, 2048 * 4, stream);
    hipMemsetAsync(maskE, 0, 1024 * 4, stream);

    // ---- CSR build ----
    const int edgeGrid = (2 * NE_N + 255) / 256;  // 7813
    histogram_kernel<<<edgeGrid, 256, 0, stream>>>(rows_1, cols_1, rows_0, cols_0, cntS, cntE);
    exscan_kernel<<<1, 1024, 0, stream>>>(cntS, S_N, offS, curS);
    exscan_kernel<<<1, 1024, 0, stream>>>(cntE, E_N, offE, curE);
    fill_kernel_xcd<<<edgeGrid * 8, 256, 0, stream>>>(
        rows_1, cols_1, vals_ui_1, vals_iu_1,
        rows_0, cols_0, vals_ui_0, vals_iu_0,
        curS, curE, csrS, csrE);

    // ---- needed-row masks (for layer 2) ----
    mark_needed<<<(B_N + 255) / 256, 256, 0, stream>>>(stu_id, B_N, maskS);
    mark_needed<<<(B_N + 255) / 256, 256, 0, stream>>>(input_ex, B_N, maskE);

    const int sGrid = (S_N + 3) / 4;
    const int eGrid = (E_N + 3) / 4;

    // ---- layer 1: inputs -> A (all rows) ----
    gather_pass<<<sGrid, 256, 0, stream>>>(exercise_emb, student_emb, d_i_1, d_i_0,
                                           offS, csrS, nullptr, statA, S_N);
    gather_pass<<<eGrid, 256, 0, stream>>>(student_emb, exercise_emb, d_j_1, d_j_0,
                                           offE, csrE, nullptr, kdiffA, E_N);

    // ---- layer 2: A -> B (only rows the batch reads) ----
    gather_pass<<<sGrid, 256, 0, stream>>>(kdiffA, statA, d_i_1, d_i_0,
                                           offS, csrS, maskS, statB, S_N);
    gather_pass<<<eGrid, 256, 0, stream>>>(statA, kdiffA, d_j_1, d_j_0,
                                           offE, csrE, maskE, kdiffB, E_N);

    // ---- prediction ----
    predict_tiled<<<B_N / 64, 512, 0, stream>>>(stu_id, input_ex, ikp, statB, kdiffB,
                                                s_bias, e_disc, W1, b1, W2, b2, W3, b3,
                                                (float*)d_out);
}

// Round 5
// 940.307 us; speedup vs baseline: 14.8693x; 1.1836x over previous
//
#include <hip/hip_runtime.h>

#define S_N 50000
#define E_N 20000
#define K_N 128
#define B_N 16384
#define NE_N 1000000

#define S_PER_XCD 6250   // ceil(S_N/8)
#define E_PER_XCD 2500   // ceil(E_N/8)

typedef short bf16x8 __attribute__((ext_vector_type(8)));
typedef float f32x4 __attribute__((ext_vector_type(4)));

__device__ __forceinline__ float sigmoidf_(float v) {
    return 1.0f / (1.0f + __expf(-v));
}
__device__ __forceinline__ float tanh_fast(float v) {
    float e = __expf(2.0f * v);
    return 1.0f - 2.0f / (e + 1.0f);
}
// fp32 -> bf16 (round-to-nearest-even, finite inputs)
__device__ __forceinline__ unsigned short f2bf(float v) {
    unsigned u = __float_as_uint(v);
    u += 0x7fffu + ((u >> 16) & 1u);
    return (unsigned short)(u >> 16);
}

// ---- CSR build ----------------------------------------------------------

__global__ __launch_bounds__(256) void histogram_kernel(
    const int* __restrict__ r1, const int* __restrict__ c1,
    const int* __restrict__ r0, const int* __restrict__ c0,
    int* __restrict__ cntS, int* __restrict__ cntE) {
    int i = blockIdx.x * blockDim.x + threadIdx.x;
    if (i < NE_N) {
        atomicAdd(&cntS[r1[i]], 1);
        atomicAdd(&cntE[c1[i]], 1);
    } else if (i < 2 * NE_N) {
        int j = i - NE_N;
        atomicAdd(&cntS[r0[j]], 1);
        atomicAdd(&cntE[c0[j]], 1);
    }
}

// wave-shuffle exclusive scan, single workgroup of 1024 threads
__global__ __launch_bounds__(1024) void exscan_kernel(
    const int* __restrict__ cnt, int n,
    int* __restrict__ off, int* __restrict__ cur) {
    __shared__ int wsum[16];
    __shared__ int carry_s;
    const int t = threadIdx.x;
    const int lane = t & 63;
    const int wid = t >> 6;
    if (t == 0) carry_s = 0;
    __syncthreads();
    for (int base = 0; base < n; base += 1024) {
        int idx = base + t;
        int v = (idx < n) ? cnt[idx] : 0;
        int s = v;
#pragma unroll
        for (int d = 1; d < 64; d <<= 1) {
            int o = __shfl_up(s, d);
            if (lane >= d) s += o;
        }
        if (lane == 63) wsum[wid] = s;
        __syncthreads();
        if (wid == 0) {
            int ws = (lane < 16) ? wsum[lane] : 0;
#pragma unroll
            for (int d = 1; d < 16; d <<= 1) {
                int o = __shfl_up(ws, d);
                if (lane >= d) ws += o;
            }
            if (lane < 16) wsum[lane] = ws;
        }
        __syncthreads();
        int waveoff = (wid == 0) ? 0 : wsum[wid - 1];
        int excl = carry_s + waveoff + s - v;
        if (idx < n) { off[idx] = excl; cur[idx] = excl; }
        __syncthreads();
        if (t == 1023) carry_s += wsum[15];
    }
    __syncthreads();
    if (t == 0) off[n] = carry_s;
}

// XCD-partitioned scatter (see R4 notes): block b -> XCD x=b&7 writes only
// edges whose dest node is in x's range; private ~3MB CSR window stays in
// that XCD's L2 so lines assemble fully before writeback.
__global__ __launch_bounds__(256) void fill_kernel_xcd(
    const int* __restrict__ r1, const int* __restrict__ c1,
    const float* __restrict__ vui1, const float* __restrict__ viu1,
    const int* __restrict__ r0, const int* __restrict__ c0,
    const float* __restrict__ vui0, const float* __restrict__ viu0,
    int* __restrict__ curS, int* __restrict__ curE,
    int2* __restrict__ csrS, int2* __restrict__ csrE) {
    const int x = blockIdx.x & 7;
    const int chunk = blockIdx.x >> 3;
    const int i = chunk * 256 + threadIdx.x;
    if (i >= 2 * NE_N) return;
    const int sLo = x * S_PER_XCD, sHi = sLo + S_PER_XCD;
    const int eLo = x * E_PER_XCD, eHi = eLo + E_PER_XCD;
    int r, c; float a, b;
    if (i < NE_N) {
        r = r1[i]; c = c1[i]; a = vui1[i]; b = viu1[i];
    } else {
        int j = i - NE_N;
        r = r0[j]; c = c0[j]; a = vui0[j]; b = viu0[j];
    }
    if (r >= sLo && r < sHi) {
        int s = atomicAdd(&curS[r], 1);
        csrS[s] = make_int2(c, __float_as_int(a));
    }
    if (c >= eLo && c < eHi) {
        int s = atomicAdd(&curE[c], 1);
        csrE[s] = make_int2(r, __float_as_int(b));
    }
}

__global__ __launch_bounds__(256) void mark_needed(
    const int* __restrict__ ids, int n, unsigned* __restrict__ mask) {
    int i = blockIdx.x * blockDim.x + threadIdx.x;
    if (i < n) {
        int v = ids[i];
        atomicOr(&mask[v >> 5], 1u << (v & 31));
    }
}

// ---- propagation: one wave per destination row, 64 lanes x float2 ------
__global__ __launch_bounds__(256) void gather_pass(
    const float* __restrict__ src, const float* __restrict__ self,
    const float* __restrict__ dA, const float* __restrict__ dB,
    const int* __restrict__ off, const int2* __restrict__ csr,
    const unsigned* __restrict__ need,
    float* __restrict__ dst, int nrow) {
    int w = blockIdx.x * 4 + (threadIdx.x >> 6);
    int lane = threadIdx.x & 63;
    if (w >= nrow) return;
    if (need && !((need[w >> 5] >> (w & 31)) & 1u)) return;
    float d = dA[w] + dB[w];
    float2 sv = ((const float2*)(self + (size_t)w * K_N))[lane];
    float ax = sv.x * d, ay = sv.y * d;
    int i = off[w], end = off[w + 1];
    for (; i + 4 <= end; i += 4) {
        int2 e0 = csr[i], e1 = csr[i + 1], e2 = csr[i + 2], e3 = csr[i + 3];
        float2 s0 = ((const float2*)(src + (size_t)e0.x * K_N))[lane];
        float2 s1 = ((const float2*)(src + (size_t)e1.x * K_N))[lane];
        float2 s2 = ((const float2*)(src + (size_t)e2.x * K_N))[lane];
        float2 s3 = ((const float2*)(src + (size_t)e3.x * K_N))[lane];
        float v0 = __int_as_float(e0.y), v1 = __int_as_float(e1.y);
        float v2 = __int_as_float(e2.y), v3 = __int_as_float(e3.y);
        ax = fmaf(v0, s0.x, ax); ay = fmaf(v0, s0.y, ay);
        ax = fmaf(v1, s1.x, ax); ay = fmaf(v1, s1.y, ay);
        ax = fmaf(v2, s2.x, ax); ay = fmaf(v2, s2.y, ay);
        ax = fmaf(v3, s3.x, ax); ay = fmaf(v3, s3.y, ay);
    }
    for (; i < end; ++i) {
        int2 e = csr[i];
        float2 s = ((const float2*)(src + (size_t)e.x * K_N))[lane];
        float v = __int_as_float(e.y);
        ax = fmaf(v, s.x, ax); ay = fmaf(v, s.y, ay);
    }
    ((float2*)(dst + (size_t)w * K_N))[lane] = make_float2(ax, ay);
}

// ---- prediction stage 0: |W| -> bf16 tables -----------------------------
__global__ __launch_bounds__(256) void absbf16_kernel(
    const float* __restrict__ W1, const float* __restrict__ W2,
    unsigned short* __restrict__ w1b, unsigned short* __restrict__ w2b) {
    int i = blockIdx.x * 256 + threadIdx.x;      // 0..65535
    if (i < 32768) {
        w1b[i] = f2bf(fabsf(W1[i]));
    } else {
        int j = i - 32768;
        w2b[j] = f2bf(fabsf(W2[j]));
    }
}

// ---- prediction stage 1: feature x -> bf16 global [B_N x 128] -----------
__global__ __launch_bounds__(256) void feature_kernel(
    const int* __restrict__ stu_id, const int* __restrict__ ex_id,
    const float* __restrict__ ikp,
    const float* __restrict__ stat, const float* __restrict__ kdiff,
    const float* __restrict__ s_bias, const float* __restrict__ e_disc,
    unsigned short* __restrict__ xg) {
    int i = blockIdx.x * 256 + threadIdx.x;      // 0 .. B_N*32-1
    int row = i >> 5;
    int k4 = (i & 31) * 4;
    int s = stu_id[row];
    int e = ex_id[row];
    float sb = s_bias[s];
    float ed = sigmoidf_(e_disc[e]);
    float4 sv = *(const float4*)(stat + (size_t)s * K_N + k4);
    float4 kv = *(const float4*)(kdiff + (size_t)e * K_N + k4);
    float4 iv = *(const float4*)(ikp + (size_t)row * K_N + k4);
    ushort4 o;
    o.x = f2bf(iv.x * (sigmoidf_(sv.x + sb) - sigmoidf_(kv.x)) * ed);
    o.y = f2bf(iv.y * (sigmoidf_(sv.y + sb) - sigmoidf_(kv.y)) * ed);
    o.z = f2bf(iv.z * (sigmoidf_(sv.z + sb) - sigmoidf_(kv.z)) * ed);
    o.w = f2bf(iv.w * (sigmoidf_(sv.w + sb) - sigmoidf_(kv.w)) * ed);
    *(ushort4*)(xg + (size_t)row * K_N + k4) = o;
}

// ---- prediction stage 2: MFMA MLP ---------------------------------------
// 32 batch rows per block, 4 waves. Wave w owns cols [w*64,w*64+64) in L1
// and [w*32,w*32+32) in L2. A-frag: m=lane&15, k=quad*8+j; D: col=lane&15,
// row=quad*4+reg (m89/m91-verified layouts).
#define H1S 264   // h1 LDS row stride in ushorts (528B: 16B-aligned, 2-way banks)

__global__ __launch_bounds__(256) void mlp_mfma(
    const unsigned short* __restrict__ xg,
    const unsigned short* __restrict__ w1b,
    const unsigned short* __restrict__ w2b,
    const float* __restrict__ b1, const float* __restrict__ b2,
    const float* __restrict__ W3, const float* __restrict__ b3,
    float* __restrict__ out) {
    __shared__ unsigned short h1b[32 * H1S];
    __shared__ float partial[4][32];

    const int t = threadIdx.x;
    const int lane = t & 63;
    const int w = t >> 6;
    const int l15 = lane & 15;
    const int quad = lane >> 4;
    const int r0 = blockIdx.x * 32;

    // ---- GEMM1: C1[32x256] = X[32x128] @ |W1|^T ----
    f32x4 acc1[2][4] = {};
    for (int ks = 0; ks < 128; ks += 32) {
        bf16x8 a[2], b[4];
#pragma unroll
        for (int mt = 0; mt < 2; ++mt)
            a[mt] = *(const bf16x8*)(xg + (size_t)(r0 + mt * 16 + l15) * K_N + ks + quad * 8);
#pragma unroll
        for (int nt = 0; nt < 4; ++nt) {
            int c = w * 64 + nt * 16 + l15;
            b[nt] = *(const bf16x8*)(w1b + (size_t)c * 128 + ks + quad * 8);
        }
#pragma unroll
        for (int mt = 0; mt < 2; ++mt)
#pragma unroll
            for (int nt = 0; nt < 4; ++nt)
                acc1[mt][nt] = __builtin_amdgcn_mfma_f32_16x16x32_bf16(
                    a[mt], b[nt], acc1[mt][nt], 0, 0, 0);
    }
    // epilogue 1: h1 = tanh(C1 + b1) -> bf16 LDS
#pragma unroll
    for (int nt = 0; nt < 4; ++nt) {
        int c = w * 64 + nt * 16 + l15;
        float bias = b1[c];
#pragma unroll
        for (int mt = 0; mt < 2; ++mt)
#pragma unroll
            for (int rg = 0; rg < 4; ++rg) {
                int row = mt * 16 + quad * 4 + rg;
                h1b[row * H1S + c] = f2bf(tanh_fast(acc1[mt][nt][rg] + bias));
            }
    }
    __syncthreads();

    // ---- GEMM2: C2[32x128] = H1[32x256] @ |W2|^T ----
    f32x4 acc2[2][2] = {};
    for (int ks = 0; ks < 256; ks += 32) {
        bf16x8 a[2], b[2];
#pragma unroll
        for (int mt = 0; mt < 2; ++mt)
            a[mt] = *(const bf16x8*)(&h1b[(mt * 16 + l15) * H1S + ks + quad * 8]);
#pragma unroll
        for (int nt = 0; nt < 2; ++nt) {
            int c = w * 32 + nt * 16 + l15;
            b[nt] = *(const bf16x8*)(w2b + (size_t)c * 256 + ks + quad * 8);
        }
#pragma unroll
        for (int mt = 0; mt < 2; ++mt)
#pragma unroll
            for (int nt = 0; nt < 2; ++nt)
                acc2[mt][nt] = __builtin_amdgcn_mfma_f32_16x16x32_bf16(
                    a[mt], b[nt], acc2[mt][nt], 0, 0, 0);
    }

    // ---- layer 3: out[r] = sigmoid( sum_c |W3[c]| tanh(C2[r,c]+b2[c]) + b3 )
    float w3v[2], b2v[2];
#pragma unroll
    for (int nt = 0; nt < 2; ++nt) {
        int c = w * 32 + nt * 16 + l15;
        w3v[nt] = fabsf(W3[c]);
        b2v[nt] = b2[c];
    }
#pragma unroll
    for (int mt = 0; mt < 2; ++mt)
#pragma unroll
        for (int rg = 0; rg < 4; ++rg) {
            float v = w3v[0] * tanh_fast(acc2[mt][0][rg] + b2v[0]) +
                      w3v[1] * tanh_fast(acc2[mt][1][rg] + b2v[1]);
            v += __shfl_xor(v, 1, 16);
            v += __shfl_xor(v, 2, 16);
            v += __shfl_xor(v, 4, 16);
            v += __shfl_xor(v, 8, 16);
            if (l15 == 0) partial[w][mt * 16 + quad * 4 + rg] = v;
        }
    __syncthreads();
    if (t < 32) {
        float v = partial[0][t] + partial[1][t] + partial[2][t] + partial[3][t];
        out[r0 + t] = sigmoidf_(v + b3[0]);
    }
}

extern "C" void kernel_launch(void* const* d_in, const int* in_sizes, int n_in,
                              void* d_out, int out_size, void* d_ws, size_t ws_size,
                              hipStream_t stream) {
    const int* stu_id        = (const int*)d_in[0];
    const int* input_ex      = (const int*)d_in[1];
    const float* ikp         = (const float*)d_in[2];
    const int* rows_1        = (const int*)d_in[3];
    const int* cols_1        = (const int*)d_in[4];
    const int* rows_0        = (const int*)d_in[5];
    const int* cols_0        = (const int*)d_in[6];
    const float* vals_ui_1   = (const float*)d_in[7];
    const float* vals_iu_1   = (const float*)d_in[8];
    const float* vals_ui_0   = (const float*)d_in[9];
    const float* vals_iu_0   = (const float*)d_in[10];
    const float* d_i_1       = (const float*)d_in[11];
    const float* d_j_1       = (const float*)d_in[12];
    const float* d_i_0       = (const float*)d_in[13];
    const float* d_j_0       = (const float*)d_in[14];
    const float* student_emb = (const float*)d_in[15];
    const float* exercise_emb= (const float*)d_in[16];
    const float* s_bias      = (const float*)d_in[17];
    const float* e_disc      = (const float*)d_in[18];
    const float* W1          = (const float*)d_in[19];
    const float* b1          = (const float*)d_in[20];
    const float* W2          = (const float*)d_in[21];
    const float* b2          = (const float*)d_in[22];
    const float* W3          = (const float*)d_in[23];
    const float* b3          = (const float*)d_in[24];

    // ---- workspace layout ----
    char* p = (char*)d_ws;
    float* statA  = (float*)p; p += (size_t)S_N * K_N * 4;
    float* kdiffA = (float*)p; p += (size_t)E_N * K_N * 4;
    float* statB  = (float*)p; p += (size_t)S_N * K_N * 4;
    float* kdiffB = (float*)p; p += (size_t)E_N * K_N * 4;
    int2* csrS    = (int2*)p;  p += (size_t)2 * NE_N * 8;
    int2* csrE    = (int2*)p;  p += (size_t)2 * NE_N * 8;
    int* cntS     = (int*)p;   p += (size_t)S_N * 4;
    int* cntE     = (int*)p;   p += (size_t)E_N * 4;
    int* offS     = (int*)p;   p += (size_t)(S_N + 1) * 4;
    int* offE     = (int*)p;   p += (size_t)(E_N + 1) * 4;
    int* curS     = (int*)p;   p += (size_t)S_N * 4;
    int* curE     = (int*)p;   p += (size_t)E_N * 4;
    unsigned* maskS = (unsigned*)p; p += 2048 * 4;
    unsigned* maskE = (unsigned*)p; p += 1024 * 4;
    // overlay scratch on buffers that are dead by prediction time:
    unsigned short* xg  = (unsigned short*)statA;   // 4 MB, statA dead after layer-2
    unsigned short* w1b = (unsigned short*)kdiffA;  // 64 KB
    unsigned short* w2b = w1b + 32768;              // 64 KB, kdiffA dead after layer-2

    // ---- zero-init counters and masks ----
    hipMemsetAsync(cntS, 0, (size_t)S_N * 4, stream);
    hipMemsetAsync(cntE, 0, (size_t)E_N * 4, stream);
    hipMemsetAsync(maskS, 0, 2048 * 4, stream);
    hipMemsetAsync(maskE, 0, 1024 * 4, stream);

    // ---- CSR build ----
    const int edgeGrid = (2 * NE_N + 255) / 256;  // 7813
    histogram_kernel<<<edgeGrid, 256, 0, stream>>>(rows_1, cols_1, rows_0, cols_0, cntS, cntE);
    exscan_kernel<<<1, 1024, 0, stream>>>(cntS, S_N, offS, curS);
    exscan_kernel<<<1, 1024, 0, stream>>>(cntE, E_N, offE, curE);
    fill_kernel_xcd<<<edgeGrid * 8, 256, 0, stream>>>(
        rows_1, cols_1, vals_ui_1, vals_iu_1,
        rows_0, cols_0, vals_ui_0, vals_iu_0,
        curS, curE, csrS, csrE);

    // ---- needed-row masks (for layer 2) ----
    mark_needed<<<(B_N + 255) / 256, 256, 0, stream>>>(stu_id, B_N, maskS);
    mark_needed<<<(B_N + 255) / 256, 256, 0, stream>>>(input_ex, B_N, maskE);

    const int sGrid = (S_N + 3) / 4;
    const int eGrid = (E_N + 3) / 4;

    // ---- layer 1: inputs -> A (all rows) ----
    gather_pass<<<sGrid, 256, 0, stream>>>(exercise_emb, student_emb, d_i_1, d_i_0,
                                           offS, csrS, nullptr, statA, S_N);
    gather_pass<<<eGrid, 256, 0, stream>>>(student_emb, exercise_emb, d_j_1, d_j_0,
                                           offE, csrE, nullptr, kdiffA, E_N);

    // ---- layer 2: A -> B (only rows the batch reads) ----
    gather_pass<<<sGrid, 256, 0, stream>>>(kdiffA, statA, d_i_1, d_i_0,
                                           offS, csrS, maskS, statB, S_N);
    gather_pass<<<eGrid, 256, 0, stream>>>(statA, kdiffA, d_j_1, d_j_0,
                                           offE, csrE, maskE, kdiffB, E_N);

    // ---- prediction: feature -> bf16, |W| -> bf16, MFMA MLP ----
    // (xg/w1b/w2b overlay statA/kdiffA, so these must run after the gathers)
    feature_kernel<<<B_N * 32 / 256, 256, 0, stream>>>(
        stu_id, input_ex, ikp, statB, kdiffB, s_bias, e_disc, xg);
    absbf16_kernel<<<256, 256, 0, stream>>>(W1, W2, w1b, w2b);
    mlp_mfma<<<B_N / 32, 256, 0, stream>>>(xg, w1b, w2b, b1, b2, W3, b3,
                                           (float*)d_out);
}